// Round 2
// baseline (782.203 us; speedup 1.0000x reference)
//
#include <hip/hip_runtime.h>

#define NN 50000
#define EE 800000
#define HEADS 8
#define NEG 0.2f
#define BN_EPS 1e-5f

typedef unsigned int uint;
typedef unsigned short ushort;

typedef __bf16 bf16x8 __attribute__((ext_vector_type(8)));
typedef float f32x4 __attribute__((ext_vector_type(4)));

__device__ __forceinline__ float bflo(uint u) { return __uint_as_float(u << 16); }
__device__ __forceinline__ float bfhi(uint u) { return __uint_as_float(u & 0xffff0000u); }
__device__ __forceinline__ float bf1(ushort u) { return __uint_as_float(((uint)u) << 16); }
__device__ __forceinline__ ushort f2bf(float f) {
  uint u = __float_as_uint(f);
  u += 0x7fff + ((u >> 16) & 1);   // RTNE
  return (ushort)(u >> 16);
}
__device__ __forceinline__ float eluf(float v) { return v > 0.f ? v : expm1f(v); }

// ---------------------------------------------------------------- dtype detector
// flags[0]=1 iff x buffer is bf16 (else f32). flags[1]=1 iff edge_index is int64.
__global__ void k_detect(const uint* __restrict__ xw, const int* __restrict__ ew,
                         int* __restrict__ flags) {
  if (threadIdx.x == 0 && blockIdx.x == 0) {
    int good = 0;
    for (int i = 0; i < 256; ++i) {
      uint lo = xw[i] & 0xffffu;          // bf16 data: a value ~N(0,1); f32 data: mantissa noise
      uint ex = (lo >> 7) & 0xffu;
      if (ex >= 110u && ex <= 140u) good++;
    }
    flags[0] = (good >= 128) ? 1 : 0;
    int zeros = 0;
    for (int i = 0; i < 256; ++i)
      if (ew[2 * i + 1] == 0) zeros++;    // int64: hi words all zero
    flags[1] = (zeros >= 200) ? 1 : 0;
  }
}

// ---------------------------------------------------------------- param gather -> f32 block
// P layout (f32): att_s@0 att_d@256 c_bias@512 g_norm@768 b_norm@1024
//                 b_down@1280 g_down@1344 bb_down@1408 b_up@1472 g_up@1728 bb_up@1984
__global__ void k_params(const void* p0, const void* p1, const void* p2, const void* p3,
                         const void* p4, const void* p5, const void* p6, const void* p7,
                         const void* p8, const void* p9, const void* p10,
                         float* __restrict__ P, const int* __restrict__ flags) {
  const void* srcs[11] = {p0, p1, p2, p3, p4, p5, p6, p7, p8, p9, p10};
  const int sz[11]  = {256, 256, 256, 256, 256, 64, 64, 64, 256, 256, 256};
  const int off[11] = {0, 256, 512, 768, 1024, 1280, 1344, 1408, 1472, 1728, 1984};
  int b = blockIdx.x, t = threadIdx.x;
  if (t < sz[b]) {
    const void* s = srcs[b];
    float v = flags[0] ? bf1(((const ushort*)s)[t]) : ((const float*)s)[t];
    P[off[b] + t] = v;
  }
}

// ---------------------------------------------------------------- transpose -> bf16, zero-pad rows >= C
__global__ void k_transpose(const void* __restrict__ src, ushort* __restrict__ dst,
                            int R, int C, const int* __restrict__ flags) {
  int c = blockIdx.x;                       // dst row index; grid may exceed C (pad)
  if (c >= C) {
    for (int r = threadIdx.x; r < R; r += blockDim.x) dst[(size_t)c * R + r] = 0;
    return;
  }
  int bf = flags[0];
  for (int r = threadIdx.x; r < R; r += blockDim.x) {
    float v = bf ? bf1(((const ushort*)src)[(size_t)r * C + c])
                 : ((const float*)src)[(size_t)r * C + c];
    dst[(size_t)c * R + r] = f2bf(v);
  }
}

// ---------------------------------------------------------------- x -> bf16 (cast or passthrough)
__global__ void k_cast(const void* __restrict__ x, ushort* __restrict__ xb,
                       const int* __restrict__ flags) {
  size_t base = ((size_t)blockIdx.x * 256 + threadIdx.x) * 8;
  if (base >= (size_t)NN * 256) return;
  if (flags[0]) {
    *(uint4*)(xb + base) = *(const uint4*)((const ushort*)x + base);
  } else {
    const float* xf = (const float*)x;
    float4 a = *(const float4*)(xf + base);
    float4 b = *(const float4*)(xf + base + 4);
    uint4 o;
    o.x = (uint)f2bf(a.x) | ((uint)f2bf(a.y) << 16);
    o.y = (uint)f2bf(a.z) | ((uint)f2bf(a.w) << 16);
    o.z = (uint)f2bf(b.x) | ((uint)f2bf(b.y) << 16);
    o.w = (uint)f2bf(b.z) | ((uint)f2bf(b.w) << 16);
    *(uint4*)(xb + base) = o;
  }
}

// ---------------------------------------------------------------- edges -> canonical int32 (clamped)
__global__ void k_edges(const int* __restrict__ raw, int* __restrict__ sc, int* __restrict__ dc,
                        const int* __restrict__ flags) {
  int e = blockIdx.x * 256 + threadIdx.x;
  if (e >= EE) return;
  int s, d;
  if (flags[1]) { s = raw[2 * e]; d = raw[2 * (EE + e)]; }   // int64 lo words
  else          { s = raw[e];     d = raw[EE + e]; }
  if ((uint)s >= NN) s = 0;
  if ((uint)d >= NN) d = 0;
  sc[e] = s; dc[e] = d;
}

// ---------------------------------------------------------------- GEMM (MFMA bf16)
// C[M,*] = A[M,K] @ Bt[n,K]^T. 128x128 tile, 4 waves, 4x4 MFMA 16x16x32 each.
// mode 0: bf16 stores split: cols<256 -> o_xh, cols>=256 -> o_xres
// mode 1/2: f32 store to o_f32 [M,NC] (guard gc<NC) + f32 bias add
__global__ __launch_bounds__(256)
void k_gemm(const ushort* __restrict__ A, const ushort* __restrict__ Bt,
            int M, int K, int mode,
            ushort* __restrict__ o_xh, ushort* __restrict__ o_xres,
            float* __restrict__ o_f32, int NC, const float* __restrict__ bias) {
  __shared__ __align__(16) ushort As[128 * 32];
  __shared__ __align__(16) ushort Bs[128 * 32];
  int t = threadIdx.x;
  int l = t & 63, w = t >> 6;
  int wr = w >> 1, wc = w & 1;
  int lr = l & 15, lq = l >> 4;
  int m0 = blockIdx.x * 128;
  int n0 = blockIdx.y * 128;

  f32x4 acc[4][4];
#pragma unroll
  for (int i = 0; i < 4; ++i)
#pragma unroll
    for (int j = 0; j < 4; ++j) acc[i][j] = (f32x4){0.f, 0.f, 0.f, 0.f};

  for (int kt = 0; kt < K; kt += 32) {
    __syncthreads();
#pragma unroll
    for (int r = 0; r < 2; ++r) {   // 512 16B chunks across 256 threads
      int ci = r * 256 + t;
      int m = ci >> 2, ko = (ci & 3) << 3;
      int gm = m0 + m; gm = gm < M ? gm : M - 1;   // row clamp (pad tiles)
      *(uint4*)(&As[m * 32 + ko]) = *(const uint4*)(A + (size_t)gm * K + kt + ko);
      *(uint4*)(&Bs[m * 32 + ko]) = *(const uint4*)(Bt + (size_t)(n0 + m) * K + kt + ko);
    }
    __syncthreads();
    bf16x8 af[4], bf[4];
#pragma unroll
    for (int i = 0; i < 4; ++i) {
      af[i] = *(const bf16x8*)(&As[(wr * 64 + i * 16 + lr) * 32 + lq * 8]);
      bf[i] = *(const bf16x8*)(&Bs[(wc * 64 + i * 16 + lr) * 32 + lq * 8]);
    }
#pragma unroll
    for (int i = 0; i < 4; ++i)
#pragma unroll
      for (int j = 0; j < 4; ++j)
        acc[i][j] = __builtin_amdgcn_mfma_f32_16x16x32_bf16(af[i], bf[j], acc[i][j], 0, 0, 0);
  }

  // C/D layout: col=lane&15, row=(lane>>4)*4+reg  [m89/m91]
#pragma unroll
  for (int i = 0; i < 4; ++i) {
    int gr0 = m0 + wr * 64 + i * 16 + lq * 4;
#pragma unroll
    for (int j = 0; j < 4; ++j) {
      int gc = n0 + wc * 64 + j * 16 + lr;
#pragma unroll
      for (int r = 0; r < 4; ++r) {
        int row = gr0 + r;
        if (row >= M) continue;
        float v = acc[i][j][r];
        if (mode == 0) {
          if (gc < 256) o_xh[(size_t)row * 256 + gc] = f2bf(v);
          else          o_xres[(size_t)row * 256 + (gc - 256)] = f2bf(v);
        } else {
          if (gc < NC) o_f32[(size_t)row * NC + gc] = v + bias[gc];
        }
      }
    }
  }
}

// ---------------------------------------------------------------- attention dots (att in f32 P)
__global__ void k_attn(const ushort* __restrict__ xh, const float* __restrict__ P,
                       float* __restrict__ a_src, float* __restrict__ a_dst) {
  int id = blockIdx.x * 256 + threadIdx.x;
  if (id >= NN * HEADS) return;
  int n = id >> 3, h = id & 7;
  const uint4* xr = (const uint4*)(xh + (size_t)n * 256 + h * 32);
  const float4* pa = (const float4*)(P + h * 32);         // att_src
  const float4* pd = (const float4*)(P + 256 + h * 32);   // att_dst
  float s = 0.f, d = 0.f;
#pragma unroll
  for (int j = 0; j < 4; ++j) {
    uint4 q = xr[j];
    float4 a0 = pa[2 * j], a1 = pa[2 * j + 1];
    float4 d0 = pd[2 * j], d1 = pd[2 * j + 1];
    float x0 = bflo(q.x), x1 = bfhi(q.x), x2 = bflo(q.y), x3 = bfhi(q.y);
    float x4 = bflo(q.z), x5 = bfhi(q.z), x6 = bflo(q.w), x7 = bfhi(q.w);
    s += x0 * a0.x + x1 * a0.y + x2 * a0.z + x3 * a0.w
       + x4 * a1.x + x5 * a1.y + x6 * a1.z + x7 * a1.w;
    d += x0 * d0.x + x1 * d0.y + x2 * d0.z + x3 * d0.w
       + x4 * d1.x + x5 * d1.y + x6 * d1.z + x7 * d1.w;
  }
  a_src[id] = s; a_dst[id] = d;
}

// ---------------------------------------------------------------- edge pass: denom + degree
__global__ void k_edge(const int* __restrict__ sc, const int* __restrict__ dc,
                       const float* __restrict__ a_src, const float* __restrict__ a_dst,
                       float* __restrict__ denom, int* __restrict__ count) {
  int id = blockIdx.x * 256 + threadIdx.x;
  if (id >= EE * HEADS) return;
  int e = id >> 3, h = id & 7;
  int s = sc[e], dn = dc[e];
  float v = a_src[s * 8 + h] + a_dst[dn * 8 + h];
  v = v > 0.f ? v : NEG * v;
  v = fminf(v, 60.f);
  atomicAdd(&denom[dn * 8 + h], __expf(v));
  if (h == 0) atomicAdd(&count[dn], 1);
}

// ---------------------------------------------------------------- single-block scan -> CSR rowptr
__global__ __launch_bounds__(1024)
void k_scan(const int* __restrict__ count, int* __restrict__ rowptr, int* __restrict__ rowwork) {
  __shared__ int buf[1024];
  int t = threadIdx.x;
  const int chunk = (NN + 1023) >> 10;
  int i0 = t * chunk, i1 = i0 + chunk;
  if (i1 > NN) i1 = NN;
  if (i0 > NN) i0 = NN;
  int s = 0;
  for (int i = i0; i < i1; ++i) s += count[i];
  buf[t] = s;
  __syncthreads();
  for (int off = 1; off < 1024; off <<= 1) {
    int v = (t >= off) ? buf[t - off] : 0;
    __syncthreads();
    buf[t] += v;
    __syncthreads();
  }
  int run = buf[t] - s;
  for (int i = i0; i < i1; ++i) { rowptr[i] = run; rowwork[i] = run; run += count[i]; }
  if (t == 1023) rowptr[NN] = buf[1023];
}

// ---------------------------------------------------------------- scatter edges into CSR order
__global__ void k_scatter(const int* __restrict__ sc, const int* __restrict__ dc,
                          int* __restrict__ rowwork, int* __restrict__ perm_src) {
  int e = blockIdx.x * 256 + threadIdx.x;
  if (e >= EE) return;
  int pos = atomicAdd(&rowwork[dc[e]], 1);
  perm_src[pos] = sc[e];
}

// ---------------------------------------------------------------- gather aggregation (no atomics)
__global__ __launch_bounds__(256)
void k_aggregate(const int* __restrict__ rowptr, const int* __restrict__ perm_src,
                 const float* __restrict__ a_src, const float* __restrict__ a_dst,
                 const float* __restrict__ denom, const ushort* __restrict__ xh,
                 const ushort* __restrict__ xres, const float* __restrict__ bias,
                 float* __restrict__ out) {
  int n = blockIdx.x * 4 + (threadIdx.x >> 6);
  int l = threadIdx.x & 63;
  if (n >= NN) return;
  int h = l >> 3;
  float ad = a_dst[n * 8 + h];
  float inv = 1.0f / (denom[n * 8 + h] + 1e-16f);
  int st = rowptr[n], en = rowptr[n + 1];
  float a0 = 0.f, a1 = 0.f, a2 = 0.f, a3 = 0.f;
  for (int p = st; p < en; ++p) {
    int s = perm_src[p];
    float v = a_src[s * 8 + h] + ad;
    v = v > 0.f ? v : NEG * v;
    v = fminf(v, 60.f);
    float alpha = __expf(v) * inv;
    uint2 q = *(const uint2*)(xh + (size_t)s * 256 + l * 4);
    a0 += alpha * bflo(q.x);
    a1 += alpha * bfhi(q.x);
    a2 += alpha * bflo(q.y);
    a3 += alpha * bfhi(q.y);
  }
  int cb = l * 4;
  float4 qb = *(const float4*)(bias + cb);
  uint2 qr = *(const uint2*)(xres + (size_t)n * 256 + cb);
  float4 o;
  o.x = a0 + qb.x + bflo(qr.x);
  o.y = a1 + qb.y + bfhi(qr.x);
  o.z = a2 + qb.z + bflo(qr.y);
  o.w = a3 + qb.w + bfhi(qr.y);
  *(float4*)(out + (size_t)n * 256 + cb) = o;
}

// ---------------------------------------------------------------- BN batch stats (sum, sumsq)
__global__ void k_stats(const float* __restrict__ x, float* __restrict__ sums, int n, int C) {
  int t = threadIdx.x;
  int c = t & (C - 1);
  int rl = t / C;
  int rpb = 256 / C;
  int rows = (n + gridDim.x - 1) / gridDim.x;
  int r0 = blockIdx.x * rows;
  int r1 = r0 + rows; if (r1 > n) r1 = n;
  float s = 0.f, ss = 0.f;
  for (int r = r0 + rl; r < r1; r += rpb) {
    float v = x[(size_t)r * C + c];
    s += v; ss += v * v;
  }
  atomicAdd(&sums[c], s);
  atomicAdd(&sums[C + c], ss);
}

// ---------------------------------------------------------------- h1b = bf16(elu(bn(out_gat)))
__global__ void k_bnact1(const float* __restrict__ xin, const float* __restrict__ sums,
                         const float* __restrict__ g, const float* __restrict__ b,
                         ushort* __restrict__ h1b) {
  int id = blockIdx.x * 256 + threadIdx.x;
  size_t base = (size_t)id * 4;
  if (base >= (size_t)NN * 256) return;
  int c = (int)(base & 255);
  const float invN = 1.0f / NN;
  float4 sm = *(const float4*)(sums + c);
  float4 sq = *(const float4*)(sums + 256 + c);
  float4 g4 = *(const float4*)(g + c);
  float4 b4 = *(const float4*)(b + c);
  float4 v = *(const float4*)(xin + base);
  float vv[4] = {v.x, v.y, v.z, v.w};
  float smv[4] = {sm.x, sm.y, sm.z, sm.w}, sqv[4] = {sq.x, sq.y, sq.z, sq.w};
  float gv[4] = {g4.x, g4.y, g4.z, g4.w}, bv[4] = {b4.x, b4.y, b4.z, b4.w};
  float o[4];
#pragma unroll
  for (int j = 0; j < 4; ++j) {
    float mean = smv[j] * invN;
    float var = sqv[j] * invN - mean * mean;
    float sc = gv[j] * rsqrtf(var + BN_EPS);
    o[j] = eluf((vv[j] - mean) * sc + bv[j]);
  }
  uint2 pk;
  pk.x = (uint)f2bf(o[0]) | ((uint)f2bf(o[1]) << 16);
  pk.y = (uint)f2bf(o[2]) | ((uint)f2bf(o[3]) << 16);
  *(uint2*)(h1b + base) = pk;
}

// ---------------------------------------------------------------- d_b = bf16(elu(bn(d_pre)))
__global__ void k_bnact2(const float* __restrict__ xin, const float* __restrict__ sums,
                         const float* __restrict__ g, const float* __restrict__ b,
                         ushort* __restrict__ db) {
  int id = blockIdx.x * 256 + threadIdx.x;
  size_t base = (size_t)id * 4;
  if (base >= (size_t)NN * 64) return;
  int c = (int)(base & 63);
  const float invN = 1.0f / NN;
  float4 sm = *(const float4*)(sums + c);
  float4 sq = *(const float4*)(sums + 64 + c);
  float4 g4 = *(const float4*)(g + c);
  float4 b4 = *(const float4*)(b + c);
  float4 v = *(const float4*)(xin + base);
  float vv[4] = {v.x, v.y, v.z, v.w};
  float smv[4] = {sm.x, sm.y, sm.z, sm.w}, sqv[4] = {sq.x, sq.y, sq.z, sq.w};
  float gv[4] = {g4.x, g4.y, g4.z, g4.w}, bv[4] = {b4.x, b4.y, b4.z, b4.w};
  float o[4];
#pragma unroll
  for (int j = 0; j < 4; ++j) {
    float mean = smv[j] * invN;
    float var = sqv[j] * invN - mean * mean;
    float sc = gv[j] * rsqrtf(var + BN_EPS);
    o[j] = eluf((vv[j] - mean) * sc + bv[j]);
  }
  uint2 pk;
  pk.x = (uint)f2bf(o[0]) | ((uint)f2bf(o[1]) << 16);
  pk.y = (uint)f2bf(o[2]) | ((uint)f2bf(o[3]) << 16);
  *(uint2*)(db + base) = pk;
}

// ---------------------------------------------------------------- out = h1 + elu(bn(u_pre)) + x
__global__ void k_final(const float* __restrict__ upre, const float* __restrict__ sums,
                        const float* __restrict__ g, const float* __restrict__ b,
                        const ushort* __restrict__ h1b, const void* __restrict__ xsrc,
                        void* __restrict__ outv, const int* __restrict__ flags) {
  int id = blockIdx.x * 256 + threadIdx.x;
  size_t base = (size_t)id * 4;
  if (base >= (size_t)NN * 256) return;
  int c = (int)(base & 255);
  const float invN = 1.0f / NN;
  float4 sm = *(const float4*)(sums + c);
  float4 sq = *(const float4*)(sums + 256 + c);
  float4 g4 = *(const float4*)(g + c);
  float4 b4 = *(const float4*)(b + c);
  float4 v = *(const float4*)(upre + base);
  uint2 qh = *(const uint2*)(h1b + base);
  float xv[4];
  if (flags[0]) {
    uint2 qx = *(const uint2*)((const ushort*)xsrc + base);
    xv[0] = bflo(qx.x); xv[1] = bfhi(qx.x); xv[2] = bflo(qx.y); xv[3] = bfhi(qx.y);
  } else {
    float4 qx = *(const float4*)((const float*)xsrc + base);
    xv[0] = qx.x; xv[1] = qx.y; xv[2] = qx.z; xv[3] = qx.w;
  }
  float vv[4] = {v.x, v.y, v.z, v.w};
  float hv[4] = {bflo(qh.x), bfhi(qh.x), bflo(qh.y), bfhi(qh.y)};
  float smv[4] = {sm.x, sm.y, sm.z, sm.w}, sqv[4] = {sq.x, sq.y, sq.z, sq.w};
  float gv[4] = {g4.x, g4.y, g4.z, g4.w}, bv[4] = {b4.x, b4.y, b4.z, b4.w};
  float o[4];
#pragma unroll
  for (int j = 0; j < 4; ++j) {
    float mean = smv[j] * invN;
    float var = sqv[j] * invN - mean * mean;
    float sc = gv[j] * rsqrtf(var + BN_EPS);
    o[j] = eluf((vv[j] - mean) * sc + bv[j]) + hv[j] + xv[j];
  }
  if (flags[0]) {
    uint2 pk;
    pk.x = (uint)f2bf(o[0]) | ((uint)f2bf(o[1]) << 16);
    pk.y = (uint)f2bf(o[2]) | ((uint)f2bf(o[3]) << 16);
    *(uint2*)((ushort*)outv + base) = pk;
  } else {
    *(float4*)((float*)outv + base) = make_float4(o[0], o[1], o[2], o[3]);
  }
}

// ================================================================ host
extern "C" void kernel_launch(void* const* d_in, const int* in_sizes, int n_in,
                              void* d_out, int out_size, void* d_ws, size_t ws_size,
                              hipStream_t stream) {
  const void* x      = d_in[0];
  const int*  ei     = (const int*)d_in[1];
  const void* W_lin  = d_in[2];
  const void* att_s  = d_in[3];
  const void* att_d  = d_in[4];
  const void* c_bias = d_in[5];
  const void* W_res  = d_in[6];
  const void* g_norm = d_in[7];
  const void* b_norm = d_in[8];
  const void* W_down = d_in[9];
  const void* b_down = d_in[10];
  const void* g_down = d_in[11];
  const void* bb_down= d_in[12];
  const void* W_up   = d_in[13];
  const void* b_up   = d_in[14];
  const void* g_up   = d_in[15];
  const void* bb_up  = d_in[16];

  char* ws = (char*)d_ws;
  size_t off = 0;
  auto alloc = [&](size_t bytes) -> char* {
    char* p = ws + off;
    off = (off + bytes + 255) & ~(size_t)255;
    return p;
  };
  // ---- zeroed region
  int*   flags  = (int*)alloc(2 * 4);
  float* denom  = (float*)alloc((size_t)NN * 8 * 4);
  int*   count  = (int*)alloc((size_t)NN * 4);
  float* sums1  = (float*)alloc(512 * 4);
  float* sums2  = (float*)alloc(128 * 4);
  float* sums3  = (float*)alloc(512 * 4);
  size_t zbytes = off;
  // ---- rest
  float* P      = (float*)alloc(2240 * 4);
  int* rowptr   = (int*)alloc((size_t)(NN + 1) * 4);
  int* rowwork  = (int*)alloc((size_t)(NN + 1) * 4);
  int* src_c    = (int*)alloc((size_t)EE * 4);
  int* dst_c    = (int*)alloc((size_t)EE * 4);
  int* perm_src = (int*)alloc((size_t)EE * 4);
  ushort* bt1   = (ushort*)alloc((size_t)512 * 256 * 2);
  ushort* bt2   = (ushort*)alloc((size_t)128 * 256 * 2);  // rows 64..127 zero-padded
  ushort* bt3   = (ushort*)alloc((size_t)256 * 64 * 2);
  float* a_src  = (float*)alloc((size_t)NN * 8 * 4);
  float* a_dst  = (float*)alloc((size_t)NN * 8 * 4);
  ushort* x_bf  = (ushort*)alloc((size_t)NN * 256 * 2);
  ushort* xh    = (ushort*)alloc((size_t)NN * 256 * 2);
  ushort* xres  = (ushort*)alloc((size_t)NN * 256 * 2);
  float* out_gat= (float*)alloc((size_t)NN * 256 * 4);
  ushort* d_b   = (ushort*)alloc((size_t)NN * 64 * 2);
  // ---- aliases (non-overlapping lifetimes)
  ushort* h1b  = x_bf;            // x_bf dead after GEMM1
  float*  d_pre = (float*)xres;   // xres dead after k_aggregate (12.8MB <= 25.6MB)
  float*  u_pre = out_gat;        // out_gat dead after k_bnact1

  hipMemsetAsync(d_ws, 0, zbytes, stream);

  hipLaunchKernelGGL(k_detect, dim3(1), dim3(64), 0, stream, (const uint*)x, ei, flags);
  hipLaunchKernelGGL(k_params, dim3(11), dim3(256), 0, stream,
                     att_s, att_d, c_bias, g_norm, b_norm, b_down, g_down, bb_down,
                     b_up, g_up, bb_up, P, flags);
  hipLaunchKernelGGL(k_transpose, dim3(256), dim3(256), 0, stream, W_lin, bt1, 256, 256, flags);
  hipLaunchKernelGGL(k_transpose, dim3(256), dim3(256), 0, stream, W_res, bt1 + 256 * 256, 256, 256, flags);
  hipLaunchKernelGGL(k_transpose, dim3(128), dim3(256), 0, stream, W_down, bt2, 256, 64, flags);
  hipLaunchKernelGGL(k_transpose, dim3(256), dim3(64),  0, stream, W_up, bt3, 64, 256, flags);
  hipLaunchKernelGGL(k_cast, dim3(6250), dim3(256), 0, stream, x, x_bf, flags);
  hipLaunchKernelGGL(k_edges, dim3((EE + 255) / 256), dim3(256), 0, stream, ei, src_c, dst_c, flags);

  // GEMM1: [xh | xres] = x @ [W_lin | W_res]
  hipLaunchKernelGGL(k_gemm, dim3(391, 4), dim3(256), 0, stream, x_bf, bt1, NN, 256, 0,
                     xh, xres, (float*)nullptr, 0, (const float*)nullptr);
  hipLaunchKernelGGL(k_attn, dim3((NN * 8 + 255) / 256), dim3(256), 0, stream,
                     xh, P, a_src, a_dst);
  hipLaunchKernelGGL(k_edge, dim3(EE * 8 / 256), dim3(256), 0, stream,
                     src_c, dst_c, a_src, a_dst, denom, count);
  hipLaunchKernelGGL(k_scan, dim3(1), dim3(1024), 0, stream, count, rowptr, rowwork);
  hipLaunchKernelGGL(k_scatter, dim3((EE + 255) / 256), dim3(256), 0, stream,
                     src_c, dst_c, rowwork, perm_src);
  hipLaunchKernelGGL(k_aggregate, dim3(NN / 4), dim3(256), 0, stream, rowptr, perm_src,
                     a_src, a_dst, denom, xh, xres, P + 512, out_gat);

  hipLaunchKernelGGL(k_stats, dim3(256), dim3(256), 0, stream, out_gat, sums1, NN, 256);
  hipLaunchKernelGGL(k_bnact1, dim3(NN * 256 / 4 / 256), dim3(256), 0, stream,
                     out_gat, sums1, P + 768, P + 1024, h1b);

  // GEMM2: d_pre = h1 @ W_down + b_down
  hipLaunchKernelGGL(k_gemm, dim3(391, 1), dim3(256), 0, stream, h1b, bt2, NN, 256, 1,
                     (ushort*)nullptr, (ushort*)nullptr, d_pre, 64, P + 1280);
  hipLaunchKernelGGL(k_stats, dim3(256), dim3(256), 0, stream, d_pre, sums2, NN, 64);
  hipLaunchKernelGGL(k_bnact2, dim3(NN * 64 / 4 / 256), dim3(256), 0, stream,
                     d_pre, sums2, P + 1344, P + 1408, d_b);

  // GEMM3: u_pre = d @ W_up + b_up
  hipLaunchKernelGGL(k_gemm, dim3(391, 2), dim3(256), 0, stream, d_b, bt3, NN, 64, 2,
                     (ushort*)nullptr, (ushort*)nullptr, u_pre, 256, P + 1472);
  hipLaunchKernelGGL(k_stats, dim3(256), dim3(256), 0, stream, u_pre, sums3, NN, 256);
  hipLaunchKernelGGL(k_final, dim3(NN * 256 / 4 / 256), dim3(256), 0, stream,
                     u_pre, sums3, P + 1728, P + 1984, h1b, x, d_out, flags);
}

// Round 3
// 648.526 us; speedup vs baseline: 1.2061x; 1.2061x over previous
//
#include <hip/hip_runtime.h>

#define NN 50000
#define EE 800000
#define HEADS 8
#define NEG 0.2f
#define BN_EPS 1e-5f
#define SCAN_B 196   // ceil(NN/256)

typedef unsigned int uint;
typedef unsigned short ushort;

typedef __bf16 bf16x8 __attribute__((ext_vector_type(8)));
typedef float f32x4 __attribute__((ext_vector_type(4)));

__device__ __forceinline__ float bflo(uint u) { return __uint_as_float(u << 16); }
__device__ __forceinline__ float bfhi(uint u) { return __uint_as_float(u & 0xffff0000u); }
__device__ __forceinline__ float bf1(ushort u) { return __uint_as_float(((uint)u) << 16); }
__device__ __forceinline__ ushort f2bf(float f) {
  uint u = __float_as_uint(f);
  u += 0x7fff + ((u >> 16) & 1);   // RTNE
  return (ushort)(u >> 16);
}
__device__ __forceinline__ float eluf(float v) { return v > 0.f ? v : expm1f(v); }

// ---------------------------------------------------------------- dtype detector
// flags[0]=1 iff x buffer is bf16 (else f32). flags[1]=1 iff edge_index is int64.
__global__ void k_detect(const uint* __restrict__ xw, const int* __restrict__ ew,
                         int* __restrict__ flags) {
  if (threadIdx.x == 0 && blockIdx.x == 0) {
    int good = 0;
    for (int i = 0; i < 256; ++i) {
      uint lo = xw[i] & 0xffffu;
      uint ex = (lo >> 7) & 0xffu;
      if (ex >= 110u && ex <= 140u) good++;
    }
    flags[0] = (good >= 128) ? 1 : 0;
    int zeros = 0;
    for (int i = 0; i < 256; ++i)
      if (ew[2 * i + 1] == 0) zeros++;
    flags[1] = (zeros >= 200) ? 1 : 0;
  }
}

// ---------------------------------------------------------------- param gather -> f32 block
// P layout (f32): att_s@0 att_d@256 c_bias@512 g_norm@768 b_norm@1024
//                 b_down@1280 g_down@1344 bb_down@1408 b_up@1472 g_up@1728 bb_up@1984
__global__ void k_params(const void* p0, const void* p1, const void* p2, const void* p3,
                         const void* p4, const void* p5, const void* p6, const void* p7,
                         const void* p8, const void* p9, const void* p10,
                         float* __restrict__ P, const int* __restrict__ flags) {
  const void* srcs[11] = {p0, p1, p2, p3, p4, p5, p6, p7, p8, p9, p10};
  const int sz[11]  = {256, 256, 256, 256, 256, 64, 64, 64, 256, 256, 256};
  const int off[11] = {0, 256, 512, 768, 1024, 1280, 1344, 1408, 1472, 1728, 1984};
  int b = blockIdx.x, t = threadIdx.x;
  if (t < sz[b]) {
    const void* s = srcs[b];
    float v = flags[0] ? bf1(((const ushort*)s)[t]) : ((const float*)s)[t];
    P[off[b] + t] = v;
  }
}

// ---------------------------------------------------------------- transpose -> bf16, zero-pad rows >= C
__global__ void k_transpose(const void* __restrict__ src, ushort* __restrict__ dst,
                            int R, int C, const int* __restrict__ flags) {
  int c = blockIdx.x;
  if (c >= C) {
    for (int r = threadIdx.x; r < R; r += blockDim.x) dst[(size_t)c * R + r] = 0;
    return;
  }
  int bf = flags[0];
  for (int r = threadIdx.x; r < R; r += blockDim.x) {
    float v = bf ? bf1(((const ushort*)src)[(size_t)r * C + c])
                 : ((const float*)src)[(size_t)r * C + c];
    dst[(size_t)c * R + r] = f2bf(v);
  }
}

// ---------------------------------------------------------------- x -> bf16 (cast or passthrough)
__global__ void k_cast(const void* __restrict__ x, ushort* __restrict__ xb,
                       const int* __restrict__ flags) {
  size_t base = ((size_t)blockIdx.x * 256 + threadIdx.x) * 8;
  if (base >= (size_t)NN * 256) return;
  if (flags[0]) {
    *(uint4*)(xb + base) = *(const uint4*)((const ushort*)x + base);
  } else {
    const float* xf = (const float*)x;
    float4 a = *(const float4*)(xf + base);
    float4 b = *(const float4*)(xf + base + 4);
    uint4 o;
    o.x = (uint)f2bf(a.x) | ((uint)f2bf(a.y) << 16);
    o.y = (uint)f2bf(a.z) | ((uint)f2bf(a.w) << 16);
    o.z = (uint)f2bf(b.x) | ((uint)f2bf(b.y) << 16);
    o.w = (uint)f2bf(b.z) | ((uint)f2bf(b.w) << 16);
    *(uint4*)(xb + base) = o;
  }
}

// ---------------------------------------------------------------- edges -> canonical int32 + degree count
__global__ void k_edges(const int* __restrict__ raw, int* __restrict__ sc, int* __restrict__ dc,
                        int* __restrict__ count, const int* __restrict__ flags) {
  int e = blockIdx.x * 256 + threadIdx.x;
  if (e >= EE) return;
  int s, d;
  if (flags[1]) { s = raw[2 * e]; d = raw[2 * (EE + e)]; }   // int64 lo words
  else          { s = raw[e];     d = raw[EE + e]; }
  if ((uint)s >= NN) s = 0;
  if ((uint)d >= NN) d = 0;
  sc[e] = s; dc[e] = d;
  atomicAdd(&count[d], 1);
}

// ---------------------------------------------------------------- GEMM (MFMA bf16)
// C[M,*] = A[M,K] @ Bt[n,K]^T. 128x128 tile, 4 waves, 4x4 MFMA 16x16x32 each.
// mode 0: bf16 stores split: cols<256 -> o_xh, cols>=256 -> o_xres
// mode 1/2: f32 store to o_f32 [M,NC] (guard gc<NC) + f32 bias add
__global__ __launch_bounds__(256)
void k_gemm(const ushort* __restrict__ A, const ushort* __restrict__ Bt,
            int M, int K, int mode,
            ushort* __restrict__ o_xh, ushort* __restrict__ o_xres,
            float* __restrict__ o_f32, int NC, const float* __restrict__ bias) {
  __shared__ __align__(16) ushort As[128 * 32];
  __shared__ __align__(16) ushort Bs[128 * 32];
  int t = threadIdx.x;
  int l = t & 63, w = t >> 6;
  int wr = w >> 1, wc = w & 1;
  int lr = l & 15, lq = l >> 4;
  int m0 = blockIdx.x * 128;
  int n0 = blockIdx.y * 128;

  f32x4 acc[4][4];
#pragma unroll
  for (int i = 0; i < 4; ++i)
#pragma unroll
    for (int j = 0; j < 4; ++j) acc[i][j] = (f32x4){0.f, 0.f, 0.f, 0.f};

  for (int kt = 0; kt < K; kt += 32) {
    __syncthreads();
#pragma unroll
    for (int r = 0; r < 2; ++r) {
      int ci = r * 256 + t;
      int m = ci >> 2, ko = (ci & 3) << 3;
      int gm = m0 + m; gm = gm < M ? gm : M - 1;
      *(uint4*)(&As[m * 32 + ko]) = *(const uint4*)(A + (size_t)gm * K + kt + ko);
      *(uint4*)(&Bs[m * 32 + ko]) = *(const uint4*)(Bt + (size_t)(n0 + m) * K + kt + ko);
    }
    __syncthreads();
    bf16x8 af[4], bf[4];
#pragma unroll
    for (int i = 0; i < 4; ++i) {
      af[i] = *(const bf16x8*)(&As[(wr * 64 + i * 16 + lr) * 32 + lq * 8]);
      bf[i] = *(const bf16x8*)(&Bs[(wc * 64 + i * 16 + lr) * 32 + lq * 8]);
    }
#pragma unroll
    for (int i = 0; i < 4; ++i)
#pragma unroll
      for (int j = 0; j < 4; ++j)
        acc[i][j] = __builtin_amdgcn_mfma_f32_16x16x32_bf16(af[i], bf[j], acc[i][j], 0, 0, 0);
  }

  // C/D layout: col=lane&15, row=(lane>>4)*4+reg  [m89/m91]
#pragma unroll
  for (int i = 0; i < 4; ++i) {
    int gr0 = m0 + wr * 64 + i * 16 + lq * 4;
#pragma unroll
    for (int j = 0; j < 4; ++j) {
      int gc = n0 + wc * 64 + j * 16 + lr;
#pragma unroll
      for (int r = 0; r < 4; ++r) {
        int row = gr0 + r;
        if (row >= M) continue;
        float v = acc[i][j][r];
        if (mode == 0) {
          if (gc < 256) o_xh[(size_t)row * 256 + gc] = f2bf(v);
          else          o_xres[(size_t)row * 256 + (gc - 256)] = f2bf(v);
        } else {
          if (gc < NC) o_f32[(size_t)row * NC + gc] = v + bias[gc];
        }
      }
    }
  }
}

// ---------------------------------------------------------------- attention dots
__global__ void k_attn(const ushort* __restrict__ xh, const float* __restrict__ P,
                       float* __restrict__ a_src, float* __restrict__ a_dst) {
  int id = blockIdx.x * 256 + threadIdx.x;
  if (id >= NN * HEADS) return;
  int n = id >> 3, h = id & 7;
  const uint4* xr = (const uint4*)(xh + (size_t)n * 256 + h * 32);
  const float4* pa = (const float4*)(P + h * 32);         // att_src
  const float4* pd = (const float4*)(P + 256 + h * 32);   // att_dst
  float s = 0.f, d = 0.f;
#pragma unroll
  for (int j = 0; j < 4; ++j) {
    uint4 q = xr[j];
    float4 a0 = pa[2 * j], a1 = pa[2 * j + 1];
    float4 d0 = pd[2 * j], d1 = pd[2 * j + 1];
    float x0 = bflo(q.x), x1 = bfhi(q.x), x2 = bflo(q.y), x3 = bfhi(q.y);
    float x4 = bflo(q.z), x5 = bfhi(q.z), x6 = bflo(q.w), x7 = bfhi(q.w);
    s += x0 * a0.x + x1 * a0.y + x2 * a0.z + x3 * a0.w
       + x4 * a1.x + x5 * a1.y + x6 * a1.z + x7 * a1.w;
    d += x0 * d0.x + x1 * d0.y + x2 * d0.z + x3 * d0.w
       + x4 * d1.x + x5 * d1.y + x6 * d1.z + x7 * d1.w;
  }
  a_src[id] = s; a_dst[id] = d;
}

// ---------------------------------------------------------------- hierarchical scan (3 kernels)
__global__ void k_scan_bs(const int* __restrict__ count, int* __restrict__ bsum) {
  __shared__ int s[256];
  int i = blockIdx.x * 256 + threadIdx.x;
  s[threadIdx.x] = (i < NN) ? count[i] : 0;
  __syncthreads();
  for (int off = 128; off > 0; off >>= 1) {
    if (threadIdx.x < off) s[threadIdx.x] += s[threadIdx.x + off];
    __syncthreads();
  }
  if (threadIdx.x == 0) bsum[blockIdx.x] = s[0];
}

__global__ void k_scan_top(const int* __restrict__ bsum, int* __restrict__ boff,
                           int* __restrict__ rowptr) {
  __shared__ int s[256];
  int t = threadIdx.x;
  int v = (t < SCAN_B) ? bsum[t] : 0;
  s[t] = v;
  __syncthreads();
  for (int off = 1; off < 256; off <<= 1) {
    int u = (t >= off) ? s[t - off] : 0;
    __syncthreads();
    s[t] += u;
    __syncthreads();
  }
  boff[t] = s[t] - v;              // exclusive
  if (t == 255) rowptr[NN] = s[255];
}

__global__ void k_scan_wr(const int* __restrict__ count, const int* __restrict__ boff,
                          int* __restrict__ rowptr, int* __restrict__ rowwork) {
  __shared__ int s[256];
  int b = blockIdx.x, t = threadIdx.x;
  int i = b * 256 + t;
  int v = (i < NN) ? count[i] : 0;
  s[t] = v;
  __syncthreads();
  for (int off = 1; off < 256; off <<= 1) {
    int u = (t >= off) ? s[t - off] : 0;
    __syncthreads();
    s[t] += u;
    __syncthreads();
  }
  if (i < NN) {
    int ex = boff[b] + s[t] - v;
    rowptr[i] = ex;
    rowwork[i] = ex;
  }
}

// ---------------------------------------------------------------- scatter edges into CSR order
__global__ void k_scatter(const int* __restrict__ sc, const int* __restrict__ dc,
                          int* __restrict__ rowwork, int* __restrict__ perm_src) {
  int e = blockIdx.x * 256 + threadIdx.x;
  if (e >= EE) return;
  int pos = atomicAdd(&rowwork[dc[e]], 1);
  perm_src[pos] = sc[e];
}

// ---------------------------------------------------------------- gather aggregation (denom inline)
__global__ __launch_bounds__(256)
void k_aggregate(const int* __restrict__ rowptr, const int* __restrict__ perm_src,
                 const float* __restrict__ a_src, const float* __restrict__ a_dst,
                 const ushort* __restrict__ xh, const ushort* __restrict__ xres,
                 const float* __restrict__ bias, float* __restrict__ out) {
  int n = blockIdx.x * 4 + (threadIdx.x >> 6);
  int l = threadIdx.x & 63;
  if (n >= NN) return;
  int h = l >> 3;
  float ad = a_dst[n * 8 + h];
  int st = rowptr[n], en = rowptr[n + 1];
  float a0 = 0.f, a1 = 0.f, a2 = 0.f, a3 = 0.f, sum = 0.f;
  for (int p = st; p < en; ++p) {
    int s = perm_src[p];
    float v = a_src[s * 8 + h] + ad;
    v = v > 0.f ? v : NEG * v;
    v = fminf(v, 60.f);
    float wgt = __expf(v);
    sum += wgt;
    uint2 q = *(const uint2*)(xh + (size_t)s * 256 + l * 4);
    a0 += wgt * bflo(q.x);
    a1 += wgt * bfhi(q.x);
    a2 += wgt * bflo(q.y);
    a3 += wgt * bfhi(q.y);
  }
  float inv = 1.0f / (sum + 1e-16f);
  int cb = l * 4;
  float4 qb = *(const float4*)(bias + cb);
  uint2 qr = *(const uint2*)(xres + (size_t)n * 256 + cb);
  float4 o;
  o.x = a0 * inv + qb.x + bflo(qr.x);
  o.y = a1 * inv + qb.y + bfhi(qr.x);
  o.z = a2 * inv + qb.z + bflo(qr.y);
  o.w = a3 * inv + qb.w + bfhi(qr.y);
  *(float4*)(out + (size_t)n * 256 + cb) = o;
}

// ---------------------------------------------------------------- BN batch stats (sum, sumsq)
__global__ void k_stats(const float* __restrict__ x, float* __restrict__ sums, int n, int C) {
  int t = threadIdx.x;
  int c = t & (C - 1);
  int rl = t / C;
  int rpb = 256 / C;
  int rows = (n + gridDim.x - 1) / gridDim.x;
  int r0 = blockIdx.x * rows;
  int r1 = r0 + rows; if (r1 > n) r1 = n;
  float s = 0.f, ss = 0.f;
  for (int r = r0 + rl; r < r1; r += rpb) {
    float v = x[(size_t)r * C + c];
    s += v; ss += v * v;
  }
  atomicAdd(&sums[c], s);
  atomicAdd(&sums[C + c], ss);
}

// ---------------------------------------------------------------- h1b = bf16(elu(bn(out_gat)))
__global__ void k_bnact1(const float* __restrict__ xin, const float* __restrict__ sums,
                         const float* __restrict__ g, const float* __restrict__ b,
                         ushort* __restrict__ h1b) {
  int id = blockIdx.x * 256 + threadIdx.x;
  size_t base = (size_t)id * 4;
  if (base >= (size_t)NN * 256) return;
  int c = (int)(base & 255);
  const float invN = 1.0f / NN;
  float4 sm = *(const float4*)(sums + c);
  float4 sq = *(const float4*)(sums + 256 + c);
  float4 g4 = *(const float4*)(g + c);
  float4 b4 = *(const float4*)(b + c);
  float4 v = *(const float4*)(xin + base);
  float vv[4] = {v.x, v.y, v.z, v.w};
  float smv[4] = {sm.x, sm.y, sm.z, sm.w}, sqv[4] = {sq.x, sq.y, sq.z, sq.w};
  float gv[4] = {g4.x, g4.y, g4.z, g4.w}, bv[4] = {b4.x, b4.y, b4.z, b4.w};
  float o[4];
#pragma unroll
  for (int j = 0; j < 4; ++j) {
    float mean = smv[j] * invN;
    float var = sqv[j] * invN - mean * mean;
    float sc = gv[j] * rsqrtf(var + BN_EPS);
    o[j] = eluf((vv[j] - mean) * sc + bv[j]);
  }
  uint2 pk;
  pk.x = (uint)f2bf(o[0]) | ((uint)f2bf(o[1]) << 16);
  pk.y = (uint)f2bf(o[2]) | ((uint)f2bf(o[3]) << 16);
  *(uint2*)(h1b + base) = pk;
}

// ---------------------------------------------------------------- d_b = bf16(elu(bn(d_pre)))
__global__ void k_bnact2(const float* __restrict__ xin, const float* __restrict__ sums,
                         const float* __restrict__ g, const float* __restrict__ b,
                         ushort* __restrict__ db) {
  int id = blockIdx.x * 256 + threadIdx.x;
  size_t base = (size_t)id * 4;
  if (base >= (size_t)NN * 64) return;
  int c = (int)(base & 63);
  const float invN = 1.0f / NN;
  float4 sm = *(const float4*)(sums + c);
  float4 sq = *(const float4*)(sums + 64 + c);
  float4 g4 = *(const float4*)(g + c);
  float4 b4 = *(const float4*)(b + c);
  float4 v = *(const float4*)(xin + base);
  float vv[4] = {v.x, v.y, v.z, v.w};
  float smv[4] = {sm.x, sm.y, sm.z, sm.w}, sqv[4] = {sq.x, sq.y, sq.z, sq.w};
  float gv[4] = {g4.x, g4.y, g4.z, g4.w}, bv[4] = {b4.x, b4.y, b4.z, b4.w};
  float o[4];
#pragma unroll
  for (int j = 0; j < 4; ++j) {
    float mean = smv[j] * invN;
    float var = sqv[j] * invN - mean * mean;
    float sc = gv[j] * rsqrtf(var + BN_EPS);
    o[j] = eluf((vv[j] - mean) * sc + bv[j]);
  }
  uint2 pk;
  pk.x = (uint)f2bf(o[0]) | ((uint)f2bf(o[1]) << 16);
  pk.y = (uint)f2bf(o[2]) | ((uint)f2bf(o[3]) << 16);
  *(uint2*)(db + base) = pk;
}

// ---------------------------------------------------------------- out = h1 + elu(bn(u_pre)) + x
__global__ void k_final(const float* __restrict__ upre, const float* __restrict__ sums,
                        const float* __restrict__ g, const float* __restrict__ b,
                        const ushort* __restrict__ h1b, const void* __restrict__ xsrc,
                        void* __restrict__ outv, const int* __restrict__ flags) {
  int id = blockIdx.x * 256 + threadIdx.x;
  size_t base = (size_t)id * 4;
  if (base >= (size_t)NN * 256) return;
  int c = (int)(base & 255);
  const float invN = 1.0f / NN;
  float4 sm = *(const float4*)(sums + c);
  float4 sq = *(const float4*)(sums + 256 + c);
  float4 g4 = *(const float4*)(g + c);
  float4 b4 = *(const float4*)(b + c);
  float4 v = *(const float4*)(upre + base);
  uint2 qh = *(const uint2*)(h1b + base);
  float xv[4];
  if (flags[0]) {
    uint2 qx = *(const uint2*)((const ushort*)xsrc + base);
    xv[0] = bflo(qx.x); xv[1] = bfhi(qx.x); xv[2] = bflo(qx.y); xv[3] = bfhi(qx.y);
  } else {
    float4 qx = *(const float4*)((const float*)xsrc + base);
    xv[0] = qx.x; xv[1] = qx.y; xv[2] = qx.z; xv[3] = qx.w;
  }
  float vv[4] = {v.x, v.y, v.z, v.w};
  float hv[4] = {bflo(qh.x), bfhi(qh.x), bflo(qh.y), bfhi(qh.y)};
  float smv[4] = {sm.x, sm.y, sm.z, sm.w}, sqv[4] = {sq.x, sq.y, sq.z, sq.w};
  float gv[4] = {g4.x, g4.y, g4.z, g4.w}, bv[4] = {b4.x, b4.y, b4.z, b4.w};
  float o[4];
#pragma unroll
  for (int j = 0; j < 4; ++j) {
    float mean = smv[j] * invN;
    float var = sqv[j] * invN - mean * mean;
    float sc = gv[j] * rsqrtf(var + BN_EPS);
    o[j] = eluf((vv[j] - mean) * sc + bv[j]) + hv[j] + xv[j];
  }
  if (flags[0]) {
    uint2 pk;
    pk.x = (uint)f2bf(o[0]) | ((uint)f2bf(o[1]) << 16);
    pk.y = (uint)f2bf(o[2]) | ((uint)f2bf(o[3]) << 16);
    *(uint2*)((ushort*)outv + base) = pk;
  } else {
    *(float4*)((float*)outv + base) = make_float4(o[0], o[1], o[2], o[3]);
  }
}

// ================================================================ host
extern "C" void kernel_launch(void* const* d_in, const int* in_sizes, int n_in,
                              void* d_out, int out_size, void* d_ws, size_t ws_size,
                              hipStream_t stream) {
  const void* x      = d_in[0];
  const int*  ei     = (const int*)d_in[1];
  const void* W_lin  = d_in[2];
  const void* att_s  = d_in[3];
  const void* att_d  = d_in[4];
  const void* c_bias = d_in[5];
  const void* W_res  = d_in[6];
  const void* g_norm = d_in[7];
  const void* b_norm = d_in[8];
  const void* W_down = d_in[9];
  const void* b_down = d_in[10];
  const void* g_down = d_in[11];
  const void* bb_down= d_in[12];
  const void* W_up   = d_in[13];
  const void* b_up   = d_in[14];
  const void* g_up   = d_in[15];
  const void* bb_up  = d_in[16];

  char* ws = (char*)d_ws;
  size_t off = 0;
  auto alloc = [&](size_t bytes) -> char* {
    char* p = ws + off;
    off = (off + bytes + 255) & ~(size_t)255;
    return p;
  };
  // ---- zeroed region
  int*   flags  = (int*)alloc(2 * 4);
  int*   count  = (int*)alloc((size_t)NN * 4);
  float* sums1  = (float*)alloc(512 * 4);
  float* sums2  = (float*)alloc(128 * 4);
  float* sums3  = (float*)alloc(512 * 4);
  size_t zbytes = off;
  // ---- rest
  float* P      = (float*)alloc(2240 * 4);
  int* bsum     = (int*)alloc(256 * 4);
  int* boff     = (int*)alloc(256 * 4);
  int* rowptr   = (int*)alloc((size_t)(NN + 1) * 4);
  int* rowwork  = (int*)alloc((size_t)(NN + 1) * 4);
  int* src_c    = (int*)alloc((size_t)EE * 4);
  int* dst_c    = (int*)alloc((size_t)EE * 4);
  int* perm_src = (int*)alloc((size_t)EE * 4);
  ushort* bt1   = (ushort*)alloc((size_t)512 * 256 * 2);
  ushort* bt2   = (ushort*)alloc((size_t)128 * 256 * 2);  // rows 64..127 zero-padded
  ushort* bt3   = (ushort*)alloc((size_t)256 * 64 * 2);
  float* a_src  = (float*)alloc((size_t)NN * 8 * 4);
  float* a_dst  = (float*)alloc((size_t)NN * 8 * 4);
  ushort* x_bf  = (ushort*)alloc((size_t)NN * 256 * 2);
  ushort* xh    = (ushort*)alloc((size_t)NN * 256 * 2);
  ushort* xres  = (ushort*)alloc((size_t)NN * 256 * 2);
  float* out_gat= (float*)alloc((size_t)NN * 256 * 4);
  ushort* d_b   = (ushort*)alloc((size_t)NN * 64 * 2);
  // ---- aliases (non-overlapping lifetimes)
  ushort* h1b  = x_bf;            // x_bf dead after GEMM1
  float*  d_pre = (float*)xres;   // xres dead after k_aggregate
  float*  u_pre = out_gat;        // out_gat dead after k_bnact1

  hipMemsetAsync(d_ws, 0, zbytes, stream);

  hipLaunchKernelGGL(k_detect, dim3(1), dim3(64), 0, stream, (const uint*)x, ei, flags);
  hipLaunchKernelGGL(k_params, dim3(11), dim3(256), 0, stream,
                     att_s, att_d, c_bias, g_norm, b_norm, b_down, g_down, bb_down,
                     b_up, g_up, bb_up, P, flags);
  hipLaunchKernelGGL(k_transpose, dim3(256), dim3(256), 0, stream, W_lin, bt1, 256, 256, flags);
  hipLaunchKernelGGL(k_transpose, dim3(256), dim3(256), 0, stream, W_res, bt1 + 256 * 256, 256, 256, flags);
  hipLaunchKernelGGL(k_transpose, dim3(128), dim3(256), 0, stream, W_down, bt2, 256, 64, flags);
  hipLaunchKernelGGL(k_transpose, dim3(256), dim3(64),  0, stream, W_up, bt3, 64, 256, flags);
  hipLaunchKernelGGL(k_cast, dim3(6250), dim3(256), 0, stream, x, x_bf, flags);
  hipLaunchKernelGGL(k_edges, dim3((EE + 255) / 256), dim3(256), 0, stream,
                     ei, src_c, dst_c, count, flags);

  // GEMM1: [xh | xres] = x @ [W_lin | W_res]
  hipLaunchKernelGGL(k_gemm, dim3(391, 4), dim3(256), 0, stream, x_bf, bt1, NN, 256, 0,
                     xh, xres, (float*)nullptr, 0, (const float*)nullptr);
  hipLaunchKernelGGL(k_attn, dim3((NN * 8 + 255) / 256), dim3(256), 0, stream,
                     xh, P, a_src, a_dst);

  // CSR build: hierarchical scan + scatter
  hipLaunchKernelGGL(k_scan_bs, dim3(SCAN_B), dim3(256), 0, stream, count, bsum);
  hipLaunchKernelGGL(k_scan_top, dim3(1), dim3(256), 0, stream, bsum, boff, rowptr);
  hipLaunchKernelGGL(k_scan_wr, dim3(SCAN_B), dim3(256), 0, stream, count, boff, rowptr, rowwork);
  hipLaunchKernelGGL(k_scatter, dim3((EE + 255) / 256), dim3(256), 0, stream,
                     src_c, dst_c, rowwork, perm_src);

  hipLaunchKernelGGL(k_aggregate, dim3(NN / 4), dim3(256), 0, stream, rowptr, perm_src,
                     a_src, a_dst, xh, xres, P + 512, out_gat);

  hipLaunchKernelGGL(k_stats, dim3(256), dim3(256), 0, stream, out_gat, sums1, NN, 256);
  hipLaunchKernelGGL(k_bnact1, dim3(NN * 256 / 4 / 256), dim3(256), 0, stream,
                     out_gat, sums1, P + 768, P + 1024, h1b);

  // GEMM2: d_pre = h1 @ W_down + b_down
  hipLaunchKernelGGL(k_gemm, dim3(391, 1), dim3(256), 0, stream, h1b, bt2, NN, 256, 1,
                     (ushort*)nullptr, (ushort*)nullptr, d_pre, 64, P + 1280);
  hipLaunchKernelGGL(k_stats, dim3(256), dim3(256), 0, stream, d_pre, sums2, NN, 64);
  hipLaunchKernelGGL(k_bnact2, dim3(NN * 64 / 4 / 256), dim3(256), 0, stream,
                     d_pre, sums2, P + 1344, P + 1408, d_b);

  // GEMM3: u_pre = d @ W_up + b_up
  hipLaunchKernelGGL(k_gemm, dim3(391, 2), dim3(256), 0, stream, d_b, bt3, NN, 64, 2,
                     (ushort*)nullptr, (ushort*)nullptr, u_pre, 256, P + 1472);
  hipLaunchKernelGGL(k_stats, dim3(256), dim3(256), 0, stream, u_pre, sums3, NN, 256);
  hipLaunchKernelGGL(k_final, dim3(NN * 256 / 4 / 256), dim3(256), 0, stream,
                     u_pre, sums3, P + 1728, P + 1984, h1b, x, d_out, flags);
}

// Round 4
// 613.842 us; speedup vs baseline: 1.2743x; 1.0565x over previous
//
#include <hip/hip_runtime.h>

#define NN 50000
#define EE 800000
#define HEADS 8
#define NEG 0.2f
#define BN_EPS 1e-5f
#define SCAN_B 196   // ceil(NN/256)

typedef unsigned int uint;
typedef unsigned short ushort;

typedef __bf16 bf16x8 __attribute__((ext_vector_type(8)));
typedef float f32x4 __attribute__((ext_vector_type(4)));

__device__ __forceinline__ float bflo(uint u) { return __uint_as_float(u << 16); }
__device__ __forceinline__ float bfhi(uint u) { return __uint_as_float(u & 0xffff0000u); }
__device__ __forceinline__ float bf1(ushort u) { return __uint_as_float(((uint)u) << 16); }
__device__ __forceinline__ ushort f2bf(float f) {
  uint u = __float_as_uint(f);
  u += 0x7fff + ((u >> 16) & 1);   // RTNE
  return (ushort)(u >> 16);
}
__device__ __forceinline__ float eluf(float v) { return v > 0.f ? v : expm1f(v); }

// ---------------------------------------------------------------- dtype detector (1 wave)
// flags[0]=1 iff x buffer is bf16 (else f32). flags[1]=1 iff edge_index is int64.
__global__ void k_detect(const uint* __restrict__ xw, const int* __restrict__ ew,
                         int* __restrict__ flags) {
  int l = threadIdx.x;   // 64
  int good = 0, zeros = 0;
#pragma unroll
  for (int j = 0; j < 4; ++j) {
    uint lo = xw[l * 4 + j] & 0xffffu;
    uint ex = (lo >> 7) & 0xffu;
    good += (ex >= 110u && ex <= 140u) ? 1 : 0;
    zeros += (ew[2 * (l * 4 + j) + 1] == 0) ? 1 : 0;
  }
  for (int o = 32; o; o >>= 1) { good += __shfl_down(good, o); zeros += __shfl_down(zeros, o); }
  if (l == 0) { flags[0] = (good >= 128) ? 1 : 0; flags[1] = (zeros >= 200) ? 1 : 0; }
}

// ---------------------------------------------------------------- param gather -> f32 block
// P layout (f32): att_s@0 att_d@256 c_bias@512 g_norm@768 b_norm@1024
//                 b_down@1280 g_down@1344 bb_down@1408 b_up@1472 g_up@1728 bb_up@1984
__global__ void k_params(const void* p0, const void* p1, const void* p2, const void* p3,
                         const void* p4, const void* p5, const void* p6, const void* p7,
                         const void* p8, const void* p9, const void* p10,
                         float* __restrict__ P, const int* __restrict__ flags) {
  const void* srcs[11] = {p0, p1, p2, p3, p4, p5, p6, p7, p8, p9, p10};
  const int sz[11]  = {256, 256, 256, 256, 256, 64, 64, 64, 256, 256, 256};
  const int off[11] = {0, 256, 512, 768, 1024, 1280, 1344, 1408, 1472, 1728, 1984};
  int b = blockIdx.x, t = threadIdx.x;
  if (t < sz[b]) {
    const void* s = srcs[b];
    float v = flags[0] ? bf1(((const ushort*)s)[t]) : ((const float*)s)[t];
    P[off[b] + t] = v;
  }
}

// ---------------------------------------------------------------- LDS-tiled transpose -> bf16
// dst[c][r] = src[r][c] for c<C; rows C..D-1 of dst zero-filled. grid=(R/64, D/64).
__global__ void k_transpose(const void* __restrict__ src, ushort* __restrict__ dst,
                            int R, int C, int D, const int* __restrict__ flags) {
  __shared__ ushort tile[64][65];
  int r0 = blockIdx.x * 64, c0 = blockIdx.y * 64;
  int t = threadIdx.x;
  int tr = t >> 6;        // 0..3
  int tc = t & 63;
  int bf = flags[0];
#pragma unroll
  for (int i = 0; i < 16; ++i) {
    int rl = tr + i * 4;
    int r = r0 + rl, c = c0 + tc;
    float v = 0.f;
    if (r < R && c < C)
      v = bf ? bf1(((const ushort*)src)[(size_t)r * C + c])
             : ((const float*)src)[(size_t)r * C + c];
    tile[rl][tc] = f2bf(v);
  }
  __syncthreads();
#pragma unroll
  for (int i = 0; i < 16; ++i) {
    int cl = tr + i * 4;
    int rl = tc;
    int c = c0 + cl, r = r0 + rl;
    if (c < D && r < R)
      dst[(size_t)c * R + r] = (c < C) ? tile[rl][cl] : (ushort)0;
  }
}

// ---------------------------------------------------------------- x -> bf16 (cast or passthrough)
__global__ void k_cast(const void* __restrict__ x, ushort* __restrict__ xb,
                       const int* __restrict__ flags) {
  size_t base = ((size_t)blockIdx.x * 256 + threadIdx.x) * 8;
  if (base >= (size_t)NN * 256) return;
  if (flags[0]) {
    *(uint4*)(xb + base) = *(const uint4*)((const ushort*)x + base);
  } else {
    const float* xf = (const float*)x;
    float4 a = *(const float4*)(xf + base);
    float4 b = *(const float4*)(xf + base + 4);
    uint4 o;
    o.x = (uint)f2bf(a.x) | ((uint)f2bf(a.y) << 16);
    o.y = (uint)f2bf(a.z) | ((uint)f2bf(a.w) << 16);
    o.z = (uint)f2bf(b.x) | ((uint)f2bf(b.y) << 16);
    o.w = (uint)f2bf(b.z) | ((uint)f2bf(b.w) << 16);
    *(uint4*)(xb + base) = o;
  }
}

// ---------------------------------------------------------------- edges -> canonical int32 + degree count
__global__ void k_edges(const int* __restrict__ raw, int* __restrict__ sc, int* __restrict__ dc,
                        int* __restrict__ count, const int* __restrict__ flags) {
  int e = blockIdx.x * 256 + threadIdx.x;
  if (e >= EE) return;
  int s, d;
  if (flags[1]) { s = raw[2 * e]; d = raw[2 * (EE + e)]; }   // int64 lo words
  else          { s = raw[e];     d = raw[EE + e]; }
  if ((uint)s >= NN) s = 0;
  if ((uint)d >= NN) d = 0;
  sc[e] = s; dc[e] = d;
  atomicAdd(&count[d], 1);
}

// ---------------------------------------------------------------- GEMM (MFMA bf16)
// C[M,*] = A[M,K] @ Bt[n,K]^T. 128x128 tile, 4 waves, 4x4 MFMA 16x16x32 each.
// grid = (n_blocks, m_blocks): x fastest => consecutive blocks share the A-tile (L2 reuse).
// mode 0: bf16 stores split: cols<256 -> o_xh, cols>=256 -> o_xres
// mode 1/2: f32 store to o_f32 [M,NC] (guard gc<NC) + f32 bias add
__global__ __launch_bounds__(256)
void k_gemm(const ushort* __restrict__ A, const ushort* __restrict__ Bt,
            int M, int K, int mode,
            ushort* __restrict__ o_xh, ushort* __restrict__ o_xres,
            float* __restrict__ o_f32, int NC, const float* __restrict__ bias) {
  __shared__ __align__(16) ushort As[128 * 32];
  __shared__ __align__(16) ushort Bs[128 * 32];
  int t = threadIdx.x;
  int l = t & 63, w = t >> 6;
  int wr = w >> 1, wc = w & 1;
  int lr = l & 15, lq = l >> 4;
  int m0 = blockIdx.y * 128;
  int n0 = blockIdx.x * 128;

  f32x4 acc[4][4];
#pragma unroll
  for (int i = 0; i < 4; ++i)
#pragma unroll
    for (int j = 0; j < 4; ++j) acc[i][j] = (f32x4){0.f, 0.f, 0.f, 0.f};

  for (int kt = 0; kt < K; kt += 32) {
    __syncthreads();
#pragma unroll
    for (int r = 0; r < 2; ++r) {
      int ci = r * 256 + t;
      int m = ci >> 2, ko = (ci & 3) << 3;
      int gm = m0 + m; gm = gm < M ? gm : M - 1;
      *(uint4*)(&As[m * 32 + ko]) = *(const uint4*)(A + (size_t)gm * K + kt + ko);
      *(uint4*)(&Bs[m * 32 + ko]) = *(const uint4*)(Bt + (size_t)(n0 + m) * K + kt + ko);
    }
    __syncthreads();
    bf16x8 af[4], bf[4];
#pragma unroll
    for (int i = 0; i < 4; ++i) {
      af[i] = *(const bf16x8*)(&As[(wr * 64 + i * 16 + lr) * 32 + lq * 8]);
      bf[i] = *(const bf16x8*)(&Bs[(wc * 64 + i * 16 + lr) * 32 + lq * 8]);
    }
#pragma unroll
    for (int i = 0; i < 4; ++i)
#pragma unroll
      for (int j = 0; j < 4; ++j)
        acc[i][j] = __builtin_amdgcn_mfma_f32_16x16x32_bf16(af[i], bf[j], acc[i][j], 0, 0, 0);
  }

  // C/D layout: col=lane&15, row=(lane>>4)*4+reg  [m89/m91]
#pragma unroll
  for (int i = 0; i < 4; ++i) {
    int gr0 = m0 + wr * 64 + i * 16 + lq * 4;
#pragma unroll
    for (int j = 0; j < 4; ++j) {
      int gc = n0 + wc * 64 + j * 16 + lr;
#pragma unroll
      for (int r = 0; r < 4; ++r) {
        int row = gr0 + r;
        if (row >= M) continue;
        float v = acc[i][j][r];
        if (mode == 0) {
          if (gc < 256) o_xh[(size_t)row * 256 + gc] = f2bf(v);
          else          o_xres[(size_t)row * 256 + (gc - 256)] = f2bf(v);
        } else {
          if (gc < NC) o_f32[(size_t)row * NC + gc] = v + bias[gc];
        }
      }
    }
  }
}

// ---------------------------------------------------------------- attention dots
__global__ void k_attn(const ushort* __restrict__ xh, const float* __restrict__ P,
                       float* __restrict__ a_src, float* __restrict__ a_dst) {
  int id = blockIdx.x * 256 + threadIdx.x;
  if (id >= NN * HEADS) return;
  int n = id >> 3, h = id & 7;
  const uint4* xr = (const uint4*)(xh + (size_t)n * 256 + h * 32);
  const float4* pa = (const float4*)(P + h * 32);         // att_src
  const float4* pd = (const float4*)(P + 256 + h * 32);   // att_dst
  float s = 0.f, d = 0.f;
#pragma unroll
  for (int j = 0; j < 4; ++j) {
    uint4 q = xr[j];
    float4 a0 = pa[2 * j], a1 = pa[2 * j + 1];
    float4 d0 = pd[2 * j], d1 = pd[2 * j + 1];
    float x0 = bflo(q.x), x1 = bfhi(q.x), x2 = bflo(q.y), x3 = bfhi(q.y);
    float x4 = bflo(q.z), x5 = bfhi(q.z), x6 = bflo(q.w), x7 = bfhi(q.w);
    s += x0 * a0.x + x1 * a0.y + x2 * a0.z + x3 * a0.w
       + x4 * a1.x + x5 * a1.y + x6 * a1.z + x7 * a1.w;
    d += x0 * d0.x + x1 * d0.y + x2 * d0.z + x3 * d0.w
       + x4 * d1.x + x5 * d1.y + x6 * d1.z + x7 * d1.w;
  }
  a_src[id] = s; a_dst[id] = d;
}

// ---------------------------------------------------------------- hierarchical scan (3 kernels)
__global__ void k_scan_bs(const int* __restrict__ count, int* __restrict__ bsum) {
  __shared__ int s[256];
  int i = blockIdx.x * 256 + threadIdx.x;
  s[threadIdx.x] = (i < NN) ? count[i] : 0;
  __syncthreads();
  for (int off = 128; off > 0; off >>= 1) {
    if (threadIdx.x < off) s[threadIdx.x] += s[threadIdx.x + off];
    __syncthreads();
  }
  if (threadIdx.x == 0) bsum[blockIdx.x] = s[0];
}

__global__ void k_scan_top(const int* __restrict__ bsum, int* __restrict__ boff,
                           int* __restrict__ rowptr) {
  __shared__ int s[256];
  int t = threadIdx.x;
  int v = (t < SCAN_B) ? bsum[t] : 0;
  s[t] = v;
  __syncthreads();
  for (int off = 1; off < 256; off <<= 1) {
    int u = (t >= off) ? s[t - off] : 0;
    __syncthreads();
    s[t] += u;
    __syncthreads();
  }
  boff[t] = s[t] - v;              // exclusive
  if (t == 255) rowptr[NN] = s[255];
}

__global__ void k_scan_wr(const int* __restrict__ count, const int* __restrict__ boff,
                          int* __restrict__ rowptr, int* __restrict__ rowwork) {
  __shared__ int s[256];
  int b = blockIdx.x, t = threadIdx.x;
  int i = b * 256 + t;
  int v = (i < NN) ? count[i] : 0;
  s[t] = v;
  __syncthreads();
  for (int off = 1; off < 256; off <<= 1) {
    int u = (t >= off) ? s[t - off] : 0;
    __syncthreads();
    s[t] += u;
    __syncthreads();
  }
  if (i < NN) {
    int ex = boff[b] + s[t] - v;
    rowptr[i] = ex;
    rowwork[i] = ex;
  }
}

// ---------------------------------------------------------------- scatter edges into CSR order
__global__ void k_scatter(const int* __restrict__ sc, const int* __restrict__ dc,
                          int* __restrict__ rowwork, int* __restrict__ perm_src) {
  int e = blockIdx.x * 256 + threadIdx.x;
  if (e >= EE) return;
  int pos = atomicAdd(&rowwork[dc[e]], 1);
  perm_src[pos] = sc[e];
}

// ---------------------------------------------------------------- gather aggregation
// wave per dst node; half-waves take alternating edges; 16B/lane xh loads (8 ch/lane).
__global__ __launch_bounds__(256)
void k_aggregate(const int* __restrict__ rowptr, const int* __restrict__ perm_src,
                 const float* __restrict__ a_src, const float* __restrict__ a_dst,
                 const ushort* __restrict__ xh, const ushort* __restrict__ xres,
                 const float* __restrict__ bias, float* __restrict__ out) {
  int n = blockIdx.x * 4 + (threadIdx.x >> 6);
  int l = threadIdx.x & 63;
  if (n >= NN) return;
  int half = l >> 5;           // 0: even edges, 1: odd edges
  int q = l & 31;              // channels 8q..8q+7
  int h = q >> 2;              // head
  float ad = a_dst[n * 8 + h];
  int st = rowptr[n], en = rowptr[n + 1];
  float a0 = 0.f, a1 = 0.f, a2 = 0.f, a3 = 0.f;
  float a4 = 0.f, a5 = 0.f, a6 = 0.f, a7 = 0.f, sum = 0.f;
#pragma unroll 2
  for (int p = st + half; p < en; p += 2) {
    int s = perm_src[p];
    float v = a_src[s * 8 + h] + ad;
    v = v > 0.f ? v : NEG * v;
    float wgt = __expf(fminf(v, 60.f));
    sum += wgt;
    uint4 t4 = *(const uint4*)(xh + (size_t)s * 256 + q * 8);
    a0 += wgt * bflo(t4.x); a1 += wgt * bfhi(t4.x);
    a2 += wgt * bflo(t4.y); a3 += wgt * bfhi(t4.y);
    a4 += wgt * bflo(t4.z); a5 += wgt * bfhi(t4.z);
    a6 += wgt * bflo(t4.w); a7 += wgt * bfhi(t4.w);
  }
  // combine even/odd halves (lane l <-> l^32)
  sum += __shfl_xor(sum, 32);
  a0 += __shfl_xor(a0, 32); a1 += __shfl_xor(a1, 32);
  a2 += __shfl_xor(a2, 32); a3 += __shfl_xor(a3, 32);
  a4 += __shfl_xor(a4, 32); a5 += __shfl_xor(a5, 32);
  a6 += __shfl_xor(a6, 32); a7 += __shfl_xor(a7, 32);
  if (half == 0) {
    float inv = 1.0f / (sum + 1e-16f);
    int cb = q * 8;
    float4 b0 = *(const float4*)(bias + cb);
    float4 b1 = *(const float4*)(bias + cb + 4);
    uint4 qr = *(const uint4*)(xres + (size_t)n * 256 + cb);
    float4 o0, o1;
    o0.x = a0 * inv + b0.x + bflo(qr.x);
    o0.y = a1 * inv + b0.y + bfhi(qr.x);
    o0.z = a2 * inv + b0.z + bflo(qr.y);
    o0.w = a3 * inv + b0.w + bfhi(qr.y);
    o1.x = a4 * inv + b1.x + bflo(qr.z);
    o1.y = a5 * inv + b1.y + bfhi(qr.z);
    o1.z = a6 * inv + b1.z + bflo(qr.w);
    o1.w = a7 * inv + b1.w + bfhi(qr.w);
    *(float4*)(out + (size_t)n * 256 + cb) = o0;
    *(float4*)(out + (size_t)n * 256 + cb + 4) = o1;
  }
}

// ---------------------------------------------------------------- BN batch stats (sum, sumsq)
__global__ void k_stats(const float* __restrict__ x, float* __restrict__ sums, int n, int C) {
  int t = threadIdx.x;
  int c = t & (C - 1);
  int rl = t / C;
  int rpb = 256 / C;
  int rows = (n + gridDim.x - 1) / gridDim.x;
  int r0 = blockIdx.x * rows;
  int r1 = r0 + rows; if (r1 > n) r1 = n;
  float s = 0.f, ss = 0.f;
  for (int r = r0 + rl; r < r1; r += rpb) {
    float v = x[(size_t)r * C + c];
    s += v; ss += v * v;
  }
  atomicAdd(&sums[c], s);
  atomicAdd(&sums[C + c], ss);
}

// ---------------------------------------------------------------- h1b = bf16(elu(bn(out_gat)))
__global__ void k_bnact1(const float* __restrict__ xin, const float* __restrict__ sums,
                         const float* __restrict__ g, const float* __restrict__ b,
                         ushort* __restrict__ h1b) {
  int id = blockIdx.x * 256 + threadIdx.x;
  size_t base = (size_t)id * 4;
  if (base >= (size_t)NN * 256) return;
  int c = (int)(base & 255);
  const float invN = 1.0f / NN;
  float4 sm = *(const float4*)(sums + c);
  float4 sq = *(const float4*)(sums + 256 + c);
  float4 g4 = *(const float4*)(g + c);
  float4 b4 = *(const float4*)(b + c);
  float4 v = *(const float4*)(xin + base);
  float vv[4] = {v.x, v.y, v.z, v.w};
  float smv[4] = {sm.x, sm.y, sm.z, sm.w}, sqv[4] = {sq.x, sq.y, sq.z, sq.w};
  float gv[4] = {g4.x, g4.y, g4.z, g4.w}, bv[4] = {b4.x, b4.y, b4.z, b4.w};
  float o[4];
#pragma unroll
  for (int j = 0; j < 4; ++j) {
    float mean = smv[j] * invN;
    float var = sqv[j] * invN - mean * mean;
    float sc = gv[j] * rsqrtf(var + BN_EPS);
    o[j] = eluf((vv[j] - mean) * sc + bv[j]);
  }
  uint2 pk;
  pk.x = (uint)f2bf(o[0]) | ((uint)f2bf(o[1]) << 16);
  pk.y = (uint)f2bf(o[2]) | ((uint)f2bf(o[3]) << 16);
  *(uint2*)(h1b + base) = pk;
}

// ---------------------------------------------------------------- d_b = bf16(elu(bn(d_pre)))
__global__ void k_bnact2(const float* __restrict__ xin, const float* __restrict__ sums,
                         const float* __restrict__ g, const float* __restrict__ b,
                         ushort* __restrict__ db) {
  int id = blockIdx.x * 256 + threadIdx.x;
  size_t base = (size_t)id * 4;
  if (base >= (size_t)NN * 64) return;
  int c = (int)(base & 63);
  const float invN = 1.0f / NN;
  float4 sm = *(const float4*)(sums + c);
  float4 sq = *(const float4*)(sums + 64 + c);
  float4 g4 = *(const float4*)(g + c);
  float4 b4 = *(const float4*)(b + c);
  float4 v = *(const float4*)(xin + base);
  float vv[4] = {v.x, v.y, v.z, v.w};
  float smv[4] = {sm.x, sm.y, sm.z, sm.w}, sqv[4] = {sq.x, sq.y, sq.z, sq.w};
  float gv[4] = {g4.x, g4.y, g4.z, g4.w}, bv[4] = {b4.x, b4.y, b4.z, b4.w};
  float o[4];
#pragma unroll
  for (int j = 0; j < 4; ++j) {
    float mean = smv[j] * invN;
    float var = sqv[j] * invN - mean * mean;
    float sc = gv[j] * rsqrtf(var + BN_EPS);
    o[j] = eluf((vv[j] - mean) * sc + bv[j]);
  }
  uint2 pk;
  pk.x = (uint)f2bf(o[0]) | ((uint)f2bf(o[1]) << 16);
  pk.y = (uint)f2bf(o[2]) | ((uint)f2bf(o[3]) << 16);
  *(uint2*)(db + base) = pk;
}

// ---------------------------------------------------------------- out = h1 + elu(bn(u_pre)) + x
__global__ void k_final(const float* __restrict__ upre, const float* __restrict__ sums,
                        const float* __restrict__ g, const float* __restrict__ b,
                        const ushort* __restrict__ h1b, const void* __restrict__ xsrc,
                        void* __restrict__ outv, const int* __restrict__ flags) {
  int id = blockIdx.x * 256 + threadIdx.x;
  size_t base = (size_t)id * 4;
  if (base >= (size_t)NN * 256) return;
  int c = (int)(base & 255);
  const float invN = 1.0f / NN;
  float4 sm = *(const float4*)(sums + c);
  float4 sq = *(const float4*)(sums + 256 + c);
  float4 g4 = *(const float4*)(g + c);
  float4 b4 = *(const float4*)(b + c);
  float4 v = *(const float4*)(upre + base);
  uint2 qh = *(const uint2*)(h1b + base);
  float xv[4];
  if (flags[0]) {
    uint2 qx = *(const uint2*)((const ushort*)xsrc + base);
    xv[0] = bflo(qx.x); xv[1] = bfhi(qx.x); xv[2] = bflo(qx.y); xv[3] = bfhi(qx.y);
  } else {
    float4 qx = *(const float4*)((const float*)xsrc + base);
    xv[0] = qx.x; xv[1] = qx.y; xv[2] = qx.z; xv[3] = qx.w;
  }
  float vv[4] = {v.x, v.y, v.z, v.w};
  float hv[4] = {bflo(qh.x), bfhi(qh.x), bflo(qh.y), bfhi(qh.y)};
  float smv[4] = {sm.x, sm.y, sm.z, sm.w}, sqv[4] = {sq.x, sq.y, sq.z, sq.w};
  float gv[4] = {g4.x, g4.y, g4.z, g4.w}, bv[4] = {b4.x, b4.y, b4.z, b4.w};
  float o[4];
#pragma unroll
  for (int j = 0; j < 4; ++j) {
    float mean = smv[j] * invN;
    float var = sqv[j] * invN - mean * mean;
    float sc = gv[j] * rsqrtf(var + BN_EPS);
    o[j] = eluf((vv[j] - mean) * sc + bv[j]) + hv[j] + xv[j];
  }
  if (flags[0]) {
    uint2 pk;
    pk.x = (uint)f2bf(o[0]) | ((uint)f2bf(o[1]) << 16);
    pk.y = (uint)f2bf(o[2]) | ((uint)f2bf(o[3]) << 16);
    *(uint2*)((ushort*)outv + base) = pk;
  } else {
    *(float4*)((float*)outv + base) = make_float4(o[0], o[1], o[2], o[3]);
  }
}

// ================================================================ host
extern "C" void kernel_launch(void* const* d_in, const int* in_sizes, int n_in,
                              void* d_out, int out_size, void* d_ws, size_t ws_size,
                              hipStream_t stream) {
  const void* x      = d_in[0];
  const int*  ei     = (const int*)d_in[1];
  const void* W_lin  = d_in[2];
  const void* att_s  = d_in[3];
  const void* att_d  = d_in[4];
  const void* c_bias = d_in[5];
  const void* W_res  = d_in[6];
  const void* g_norm = d_in[7];
  const void* b_norm = d_in[8];
  const void* W_down = d_in[9];
  const void* b_down = d_in[10];
  const void* g_down = d_in[11];
  const void* bb_down= d_in[12];
  const void* W_up   = d_in[13];
  const void* b_up   = d_in[14];
  const void* g_up   = d_in[15];
  const void* bb_up  = d_in[16];

  char* ws = (char*)d_ws;
  size_t off = 0;
  auto alloc = [&](size_t bytes) -> char* {
    char* p = ws + off;
    off = (off + bytes + 255) & ~(size_t)255;
    return p;
  };
  // ---- zeroed region
  int*   flags  = (int*)alloc(2 * 4);
  int*   count  = (int*)alloc((size_t)NN * 4);
  float* sums1  = (float*)alloc(512 * 4);
  float* sums2  = (float*)alloc(128 * 4);
  float* sums3  = (float*)alloc(512 * 4);
  size_t zbytes = off;
  // ---- rest
  float* P      = (float*)alloc(2240 * 4);
  int* bsum     = (int*)alloc(256 * 4);
  int* boff     = (int*)alloc(256 * 4);
  int* rowptr   = (int*)alloc((size_t)(NN + 1) * 4);
  int* rowwork  = (int*)alloc((size_t)(NN + 1) * 4);
  int* src_c    = (int*)alloc((size_t)EE * 4);
  int* dst_c    = (int*)alloc((size_t)EE * 4);
  int* perm_src = (int*)alloc((size_t)EE * 4);
  ushort* bt1   = (ushort*)alloc((size_t)512 * 256 * 2);
  ushort* bt2   = (ushort*)alloc((size_t)128 * 256 * 2);  // rows 64..127 zero-padded
  ushort* bt3   = (ushort*)alloc((size_t)256 * 64 * 2);
  float* a_src  = (float*)alloc((size_t)NN * 8 * 4);
  float* a_dst  = (float*)alloc((size_t)NN * 8 * 4);
  ushort* x_bf  = (ushort*)alloc((size_t)NN * 256 * 2);
  ushort* xh    = (ushort*)alloc((size_t)NN * 256 * 2);
  ushort* xres  = (ushort*)alloc((size_t)NN * 256 * 2);
  float* out_gat= (float*)alloc((size_t)NN * 256 * 4);
  ushort* d_b   = (ushort*)alloc((size_t)NN * 64 * 2);
  // ---- aliases (non-overlapping lifetimes)
  ushort* h1b  = x_bf;            // x_bf dead after GEMM1
  float*  d_pre = (float*)xres;   // xres dead after k_aggregate
  float*  u_pre = out_gat;        // out_gat dead after k_bnact1

  hipMemsetAsync(d_ws, 0, zbytes, stream);

  hipLaunchKernelGGL(k_detect, dim3(1), dim3(64), 0, stream, (const uint*)x, ei, flags);
  hipLaunchKernelGGL(k_params, dim3(11), dim3(256), 0, stream,
                     att_s, att_d, c_bias, g_norm, b_norm, b_down, g_down, bb_down,
                     b_up, g_up, bb_up, P, flags);
  hipLaunchKernelGGL(k_transpose, dim3(4, 4), dim3(256), 0, stream, W_lin, bt1, 256, 256, 256, flags);
  hipLaunchKernelGGL(k_transpose, dim3(4, 4), dim3(256), 0, stream, W_res, bt1 + 256 * 256, 256, 256, 256, flags);
  hipLaunchKernelGGL(k_transpose, dim3(4, 2), dim3(256), 0, stream, W_down, bt2, 256, 64, 128, flags);
  hipLaunchKernelGGL(k_transpose, dim3(1, 4), dim3(256), 0, stream, W_up, bt3, 64, 256, 256, flags);
  hipLaunchKernelGGL(k_cast, dim3(6250), dim3(256), 0, stream, x, x_bf, flags);
  hipLaunchKernelGGL(k_edges, dim3((EE + 255) / 256), dim3(256), 0, stream,
                     ei, src_c, dst_c, count, flags);

  // GEMM1: [xh | xres] = x @ [W_lin | W_res]   (grid x = n-blocks for A-tile L2 reuse)
  hipLaunchKernelGGL(k_gemm, dim3(4, 391), dim3(256), 0, stream, x_bf, bt1, NN, 256, 0,
                     xh, xres, (float*)nullptr, 0, (const float*)nullptr);
  hipLaunchKernelGGL(k_attn, dim3((NN * 8 + 255) / 256), dim3(256), 0, stream,
                     xh, P, a_src, a_dst);

  // CSR build: hierarchical scan + scatter
  hipLaunchKernelGGL(k_scan_bs, dim3(SCAN_B), dim3(256), 0, stream, count, bsum);
  hipLaunchKernelGGL(k_scan_top, dim3(1), dim3(256), 0, stream, bsum, boff, rowptr);
  hipLaunchKernelGGL(k_scan_wr, dim3(SCAN_B), dim3(256), 0, stream, count, boff, rowptr, rowwork);
  hipLaunchKernelGGL(k_scatter, dim3((EE + 255) / 256), dim3(256), 0, stream,
                     src_c, dst_c, rowwork, perm_src);

  hipLaunchKernelGGL(k_aggregate, dim3(NN / 4), dim3(256), 0, stream, rowptr, perm_src,
                     a_src, a_dst, xh, xres, P + 512, out_gat);

  hipLaunchKernelGGL(k_stats, dim3(256), dim3(256), 0, stream, out_gat, sums1, NN, 256);
  hipLaunchKernelGGL(k_bnact1, dim3(NN * 256 / 4 / 256), dim3(256), 0, stream,
                     out_gat, sums1, P + 768, P + 1024, h1b);

  // GEMM2: d_pre = h1 @ W_down + b_down
  hipLaunchKernelGGL(k_gemm, dim3(1, 391), dim3(256), 0, stream, h1b, bt2, NN, 256, 1,
                     (ushort*)nullptr, (ushort*)nullptr, d_pre, 64, P + 1280);
  hipLaunchKernelGGL(k_stats, dim3(256), dim3(256), 0, stream, d_pre, sums2, NN, 64);
  hipLaunchKernelGGL(k_bnact2, dim3(NN * 64 / 4 / 256), dim3(256), 0, stream,
                     d_pre, sums2, P + 1344, P + 1408, d_b);

  // GEMM3: u_pre = d @ W_up + b_up
  hipLaunchKernelGGL(k_gemm, dim3(2, 391), dim3(256), 0, stream, d_b, bt3, NN, 64, 2,
                     (ushort*)nullptr, (ushort*)nullptr, u_pre, 256, P + 1472);
  hipLaunchKernelGGL(k_stats, dim3(256), dim3(256), 0, stream, u_pre, sums3, NN, 256);
  hipLaunchKernelGGL(k_final, dim3(NN * 256 / 4 / 256), dim3(256), 0, stream,
                     u_pre, sums3, P + 1728, P + 1984, h1b, x, d_out, flags);
}